// Round 9
// baseline (487.818 us; speedup 1.0000x reference)
//
#include <hip/hip_runtime.h>
#include <stdint.h>
#include <math.h>

typedef __bf16 bf16;
typedef __bf16 bf16x8 __attribute__((ext_vector_type(8)));
typedef float  f32x4  __attribute__((ext_vector_type(4)));

#define NVALID 2080            // D*(D+1)/2 valid (h<=w) pixels
#define NCOLS  16640           // B*NVALID  (bm rows, n-dim)
#define KDIM   4096            // NS*C2D    (bm cols, k = s*128+c)

// ws layout (bytes)
#define OFF_XBT   0u           // bf16 [8][256][128] = 512 KB
#define OFF_W3B   524288u      // bf16 [512][4096] (k=s*128+c) = 4 MB
#define OFF_W2B   4718592u     // bf16 [128][512]
#define OFF_CVEC  4849664u     // f32  [128]
#define OFF_PIX   4850176u     // int  [2080]
#define OFF_W1T   4859904u     // f32  [768][128] = 393,216
#define OFF_TABW  5253120u     // f32  [2080][32][8] = 2,129,920
#define OFF_TABT  7383040u     // u8   [2080][32][8] = 532,480 (ends 7,915,520)
#define OFF_X3    8388608u     // bf16 [16640][512] = 17,039,360
#define OFF_BM    42991616u    // bf16 [16640][4096] = 136 MB (ends 179,306,496)

__device__ __forceinline__ void gload_lds16(const void* g, void* l) {
    __builtin_amdgcn_global_load_lds(
        (const __attribute__((address_space(1))) void*)g,
        (__attribute__((address_space(3))) void*)l, 16, 0, 0);
}

// Stage 16 rows x 32 k (bf16) into LDS with XOR swizzle.
__device__ __forceinline__ void stage16(const bf16* gbase, int stride, int rbase,
                                        int k0, bf16* ldsbase, int lane) {
    int row = rbase + (lane >> 2);
    int cg  = (lane & 3) ^ ((row >> 1) & 3);
    gload_lds16(gbase + (size_t)row * stride + k0 + cg * 8, ldsbase + rbase * 32);
}

__device__ __forceinline__ bf16x8 fragld(const bf16* lds, int row, int q) {
    int c = q ^ ((row >> 1) & 3);
    return *(const bf16x8*)(lds + row * 32 + c * 8);
}

// ---------------- misc mega-kernel ------------------------------------------
// grid 813: 0 = cvec+pix2hw; 1..16 = w2 cast; 17..528 = w3 transpose;
//           529..552 = w1 transpose; 553..812 = sample table
__global__ __launch_bounds__(256) void k_misc(const float* __restrict__ w1,
                                              const float* __restrict__ w2,
                                              const float* __restrict__ b2,
                                              const float* __restrict__ b3,
                                              const float* __restrict__ w3,
                                              float* __restrict__ w1T,
                                              bf16* __restrict__ w2b,
                                              bf16* __restrict__ w3b,
                                              float* __restrict__ cvec,
                                              int* __restrict__ pix2hw,
                                              float* __restrict__ tabw,
                                              uint8_t* __restrict__ tabt) {
    int tid = threadIdx.x, bx = blockIdx.x;
    if (bx == 0) {
        int wv = tid >> 6, ln = tid & 63;
        for (int c = wv; c < 128; c += 4) {
            const float* row = w2 + (size_t)c * 512 + ln * 8;
            float p = 0.f;
            #pragma unroll
            for (int k = 0; k < 8; k++) {
                float r = b3[ln * 8 + k]; r = r > 0.f ? r : 0.f;
                p += row[k] * r;
            }
            #pragma unroll
            for (int off = 32; off; off >>= 1) p += __shfl_down(p, off);
            if (ln == 0) {
                p += b2[c];
                cvec[c] = p > 0.f ? p : 0.f;
            }
        }
        for (int pix = tid; pix < NVALID; pix += 256) {
            int h = 0, base = 0;
            while (pix >= base + (64 - h)) { base += 64 - h; h++; }
            int w = h + (pix - base);
            pix2hw[pix] = h * 64 + w;
        }
    } else if (bx <= 16) {
        int i = ((bx - 1) * 256 + tid) * 16;
        #pragma unroll
        for (int j = 0; j < 16; j++) w2b[i + j] = (bf16)w2[i + j];
    } else if (bx <= 528) {
        // transpose one o row: w3[o][c][s] -> w3b[o][s*128+c]
        __shared__ float l[128 * 33];
        int o = bx - 17;
        const float* src = w3 + (size_t)o * 4096;
        #pragma unroll
        for (int m = 0; m < 16; m++) {
            int i = m * 256 + tid;
            int c = i >> 5, s = i & 31;
            l[c * 33 + s] = src[i];
        }
        __syncthreads();
        bf16* d = w3b + (size_t)o * 4096;
        #pragma unroll
        for (int m = 0; m < 16; m++) {
            int k = m * 256 + tid;
            int s = k >> 7, c = k & 127;
            d[k] = (bf16)l[c * 33 + s];
        }
    } else if (bx <= 552) {
        // w1[co][r] -> w1T[r][co], write-coalesced
        int idx0 = (bx - 529) * 4096 + tid * 16;
        int r = idx0 >> 7, co0 = idx0 & 127;
        float tmp[16];
        #pragma unroll
        for (int m = 0; m < 16; m++) tmp[m] = w1[(size_t)(co0 + m) * 768 + r];
        #pragma unroll
        for (int m = 0; m < 4; m++)
            *(f32x4*)(w1T + idx0 + m * 4) = *(const f32x4*)(tmp + m * 4);
    } else {
        // sample table: per (pix,s) 6 (t, weight) pairs, double-exact
        int idx = (bx - 553) * 256 + tid;   // p*32+s
        if (idx >= NVALID * 32) return;
        int p = idx >> 5, s = idx & 31;
        int h = 0, base = 0;
        while (p >= base + (64 - h)) { base += 64 - h; h++; }
        int w = h + (p - base);
        double sp = 4.0 * h, ep = 4.0 * (w + 1);
        double L = ep - sp + 1.0;
        double start_p = sp - L * 0.5;
        double end_p   = ep + L * 0.5;
        double step = (end_p - start_p) / 95.0;
        float*   wd = tabw + (size_t)idx * 8;
        uint8_t* td = tabt + (size_t)idx * 8;
        #pragma unroll
        for (int i = 0; i < 3; i++) {
            double pos = start_p + step * (3 * s + i);
            double tr = trunc(pos);
            double fr = pos - tr;
            int it = (int)tr;
            bool ok = (it >= 0 && it < 255);
            wd[i*2+0] = ok ? (float)((1.0 - fr) / 3.0) : 0.f;
            td[i*2+0] = (uint8_t)(ok ? it : 0);
            wd[i*2+1] = ok ? (float)(fr / 3.0) : 0.f;
            td[i*2+1] = (uint8_t)(ok ? it + 1 : 0);
        }
        wd[6] = 0.f; wd[7] = 0.f; td[6] = 0; td[7] = 0;
    }
}

// ---------------- conv1d(k=3,pad=1) + relu + cast -> xbT[b][t][c] ------------
// sb rows padded to 12 floats (48 B) so the 6-float window reads are one
// ds_read_b128 + one ds_read_b64 instead of 12 ds_read_b32.
__global__ __launch_bounds__(256) void k_conv(const float* __restrict__ base,
                                              const float* __restrict__ w1T,
                                              const float* __restrict__ b1,
                                              bf16* __restrict__ xbT) {
    __shared__ float sb[256][12];
    int ttile = blockIdx.x, b = blockIdx.y;
    int t0 = ttile * 8, tid = threadIdx.x;
    for (int ci = tid; ci < 256; ci += 256) {
        const float* src = base + (size_t)(b * 256 + ci) * 256;
        #pragma unroll
        for (int j = 0; j < 10; j++) {
            int t = t0 - 1 + j;
            sb[ci][j] = (t >= 0 && t < 256) ? src[t] : 0.f;
        }
    }
    __syncthreads();
    int co = tid & 127, th = tid >> 7;
    float bias = b1[co];
    float acc[4] = {bias, bias, bias, bias};
    const float* wt = w1T + co;
    int tl = th * 4;
    for (int ci = 0; ci < 256; ci++) {
        float wa = wt[(ci*3+0) * 128];
        float wb = wt[(ci*3+1) * 128];
        float wc = wt[(ci*3+2) * 128];
        f32x4 x0 = *(const f32x4*)&sb[ci][tl];          // tl in {0,4}: 16B-aligned
        float2 x1 = *(const float2*)&sb[ci][tl + 4];    // 8B-aligned
        float w6[6] = {x0[0], x0[1], x0[2], x0[3], x1.x, x1.y};
        #pragma unroll
        for (int j = 0; j < 4; j++)
            acc[j] += w6[j]*wa + w6[j+1]*wb + w6[j+2]*wc;
    }
    bf16* dst = xbT + ((size_t)b * 256 + t0 + tl) * 128 + co;
    #pragma unroll
    for (int j = 0; j < 4; j++) {
        float v = acc[j] > 0.f ? acc[j] : 0.f;
        dst[j * 128] = (bf16)v;
    }
}

// ---------------- bm sparse: bm[n=(b,p)][s*128+c] = sum_j w_j xbT[b][t_j][c] -
// One wave per row; half-wave s-split (lanes 0-31 -> s0, 32-63 -> s0+1),
// each lane covers 4 c via dwordx2 gathers; 16 iterations.
__global__ __launch_bounds__(256) void k_bm(const bf16* __restrict__ xbT,
                                            const float* __restrict__ tabw,
                                            const uint8_t* __restrict__ tabt,
                                            bf16* __restrict__ bm) {
    int lane = threadIdx.x & 63;
    int half = lane >> 5;
    int c4 = (lane & 31) * 4;
    int n = blockIdx.x * 4 + (threadIdx.x >> 6);
    int b = n / NVALID, p = n - b * NVALID;
    const bf16* xs = xbT + (size_t)b * 32768;
    bf16* dst = bm + (size_t)n * (size_t)KDIM;
    for (int s0 = 0; s0 < 32; s0 += 2) {
        int idx = (p * 32 + s0 + half) * 8;
        f32x4 wA = *(const f32x4*)(tabw + idx);
        float w4 = tabw[idx + 4], w5 = tabw[idx + 5];
        uint2 tt = *(const uint2*)(tabt + idx);
        float wv[6] = {wA[0], wA[1], wA[2], wA[3], w4, w5};
        int   ts[6] = {(int)(tt.x & 255), (int)((tt.x >> 8) & 255),
                       (int)((tt.x >> 16) & 255), (int)((tt.x >> 24) & 255),
                       (int)(tt.y & 255), (int)((tt.y >> 8) & 255)};
        float a0 = 0.f, a1 = 0.f, a2 = 0.f, a3 = 0.f;
        #pragma unroll
        for (int j = 0; j < 6; j++) {
            uint2 x = *(const uint2*)(xs + ts[j] * 128 + c4);
            union { uint32_t u; float f; } u0, u1, u2, u3;
            u0.u = x.x << 16; u1.u = x.x & 0xffff0000u;
            u2.u = x.y << 16; u3.u = x.y & 0xffff0000u;
            a0 += wv[j] * u0.f; a1 += wv[j] * u1.f;
            a2 += wv[j] * u2.f; a3 += wv[j] * u3.f;
        }
        union { uint2 u; bf16 h[4]; } o;
        o.h[0] = (bf16)a0; o.h[1] = (bf16)a1; o.h[2] = (bf16)a2; o.h[3] = (bf16)a3;
        *(uint2*)(dst + (s0 + half) * 128 + c4) = o.u;
    }
}

// ---------------- GEMM3 (proven): x3[n][o] = relu(w3b @ bm^T + b3) -----------
// 1-D grid 520. ids [0,512): xcd=id&7, o=(id>>3)&3, n=(id>>5)*8+xcd;
// ids [512,520): r=id-512, n=128+(r&1), o=r>>1.
__global__ __launch_bounds__(256, 2) void k_gemm3f(const bf16* __restrict__ w3b,
                                                   const bf16* __restrict__ bm,
                                                   const float* __restrict__ b3,
                                                   bf16* __restrict__ x3) {
    __shared__ __align__(16) char lds[34816];
    bf16* As0 = (bf16*)lds;
    bf16* Bs0 = (bf16*)(lds + 16384);
    bf16* T2  = (bf16*)lds;

    int tid = threadIdx.x, lane = tid & 63, wave = tid >> 6;
    int m16 = lane & 15, q = lane >> 4;
    int wm = wave >> 1, wn = wave & 1;
    int id = blockIdx.x, nt, ot;
    if (id >= 512) { int r = id - 512; nt = 128 + (r & 1); ot = r >> 1; }
    else           { nt = (id >> 5) * 8 + (id & 7); ot = (id >> 3) & 3; }
    int n0 = nt * 128, o0 = ot * 128;
    const bf16* Ag = w3b + (size_t)o0 * KDIM;
    const bf16* Bg = bm + (size_t)n0 * KDIM;

    f32x4 acc[4][4];
    #pragma unroll
    for (int i = 0; i < 4; i++)
        #pragma unroll
        for (int j = 0; j < 4; j++) acc[i][j] = (f32x4){0.f, 0.f, 0.f, 0.f};

    stage16(Ag, KDIM, wave * 32,      0, As0, lane);
    stage16(Ag, KDIM, wave * 32 + 16, 0, As0, lane);
    stage16(Bg, KDIM, wave * 32,      0, Bs0, lane);
    stage16(Bg, KDIM, wave * 32 + 16, 0, Bs0, lane);

    for (int ks = 0; ks < 128; ks++) {
        __syncthreads();
        if (ks < 127) {
            int k0 = (ks + 1) * 32, o = ((ks + 1) & 1) * 4096;
            stage16(Ag, KDIM, wave * 32,      k0, As0 + o, lane);
            stage16(Ag, KDIM, wave * 32 + 16, k0, As0 + o, lane);
            stage16(Bg, KDIM, wave * 32,      k0, Bs0 + o, lane);
            stage16(Bg, KDIM, wave * 32 + 16, k0, Bs0 + o, lane);
        }
        const bf16* Ac = As0 + (ks & 1) * 4096;
        const bf16* Bc = Bs0 + (ks & 1) * 4096;
        bf16x8 af[4], bfv[4];
        #pragma unroll
        for (int i = 0; i < 4; i++) af[i]  = fragld(Ac, wm * 64 + i * 16 + m16, q);
        #pragma unroll
        for (int j = 0; j < 4; j++) bfv[j] = fragld(Bc, wn * 64 + j * 16 + m16, q);
        #pragma unroll
        for (int i = 0; i < 4; i++)
            #pragma unroll
            for (int j = 0; j < 4; j++)
                acc[i][j] = __builtin_amdgcn_mfma_f32_16x16x32_bf16(af[i], bfv[j], acc[i][j], 0, 0, 0);
    }
    __syncthreads();
    #pragma unroll
    for (int i = 0; i < 4; i++)
        #pragma unroll
        for (int r = 0; r < 4; r++) {
            int o_l = wm * 64 + i * 16 + q * 4 + r;
            float bias = b3[o0 + o_l];
            #pragma unroll
            for (int j = 0; j < 4; j++) {
                int n_l = wn * 64 + j * 16 + m16;
                float v = acc[i][j][r] + bias; v = v > 0.f ? v : 0.f;
                T2[n_l * 136 + o_l] = (bf16)v;
            }
        }
    __syncthreads();
    {
        int n_l = tid >> 1, half = (tid & 1) * 64;
        bf16* dst = x3 + (size_t)(n0 + n_l) * 512 + o0 + half;
        const bf16* src = T2 + n_l * 136 + half;
        #pragma unroll
        for (int m = 0; m < 8; m++)
            *(bf16x8*)(dst + m * 8) = *(const bf16x8*)(src + m * 8);
    }
}

// ---------------- GEMM4 + fill: blocks [0,260) gemm, [260,1284) fill ---------
__global__ __launch_bounds__(256, 2) void k_gemm4(const bf16* __restrict__ w2b,
                                                  const bf16* __restrict__ x3,
                                                  const float* __restrict__ b2,
                                                  const int* __restrict__ pix2hw,
                                                  const float* __restrict__ cvec,
                                                  float* __restrict__ out) {
    __shared__ __align__(16) char lds[24576];
    if (blockIdx.x >= 260) {
        int bo = blockIdx.x - 260;           // b*128 + o2
        float v = cvec[bo & 127];
        float* dst = out + (size_t)bo * 4096;
        for (int hw = threadIdx.x; hw < 4096; hw += 256) {
            int h = hw >> 6, w = hw & 63;
            if (w < h) dst[hw] = v;
        }
        return;
    }
    bf16* As0 = (bf16*)lds;
    bf16* Bs0 = (bf16*)(lds + 16384);

    int tid = threadIdx.x, lane = tid & 63, wave = tid >> 6;
    int m16 = lane & 15, q = lane >> 4;
    int n0 = blockIdx.x * 64;
    const bf16* Ag = w2b;
    const bf16* Bg = x3 + (size_t)n0 * 512;

    f32x4 acc[2][4];
    #pragma unroll
    for (int i = 0; i < 2; i++)
        #pragma unroll
        for (int j = 0; j < 4; j++) acc[i][j] = (f32x4){0.f, 0.f, 0.f, 0.f};

    stage16(Ag, 512, wave * 32,      0, As0, lane);
    stage16(Ag, 512, wave * 32 + 16, 0, As0, lane);
    stage16(Bg, 512, wave * 16,      0, Bs0, lane);

    for (int ks = 0; ks < 16; ks++) {
        __syncthreads();
        if (ks < 15) {
            int k0 = (ks + 1) * 32, oA = ((ks + 1) & 1) * 4096, oB = ((ks + 1) & 1) * 2048;
            stage16(Ag, 512, wave * 32,      k0, As0 + oA, lane);
            stage16(Ag, 512, wave * 32 + 16, k0, As0 + oA, lane);
            stage16(Bg, 512, wave * 16,      k0, Bs0 + oB, lane);
        }
        const bf16* Ac = As0 + (ks & 1) * 4096;
        const bf16* Bc = Bs0 + (ks & 1) * 2048;
        bf16x8 af[2], bfv[4];
        #pragma unroll
        for (int i = 0; i < 2; i++) af[i]  = fragld(Ac, wave * 32 + i * 16 + m16, q);
        #pragma unroll
        for (int j = 0; j < 4; j++) bfv[j] = fragld(Bc, j * 16 + m16, q);
        #pragma unroll
        for (int i = 0; i < 2; i++)
            #pragma unroll
            for (int j = 0; j < 4; j++)
                acc[i][j] = __builtin_amdgcn_mfma_f32_16x16x32_bf16(af[i], bfv[j], acc[i][j], 0, 0, 0);
    }
    int barr[4], hwarr[4];
    #pragma unroll
    for (int j = 0; j < 4; j++) {
        int n = n0 + j * 16 + m16;
        int bb = n / NVALID;
        barr[j] = bb; hwarr[j] = pix2hw[n - bb * NVALID];
    }
    #pragma unroll
    for (int i = 0; i < 2; i++)
        #pragma unroll
        for (int r = 0; r < 4; r++) {
            int o2 = wave * 32 + i * 16 + q * 4 + r;
            float bias = b2[o2];
            #pragma unroll
            for (int j = 0; j < 4; j++) {
                float v = acc[i][j][r] + bias; v = v > 0.f ? v : 0.f;
                out[(size_t)barr[j] * 524288 + o2 * 4096 + hwarr[j]] = v;
            }
        }
}

extern "C" void kernel_launch(void* const* d_in, const int* in_sizes, int n_in,
                              void* d_out, int out_size, void* d_ws, size_t ws_size,
                              hipStream_t stream) {
    const float* base = (const float*)d_in[0];
    const float* w1   = (const float*)d_in[1];
    const float* b1   = (const float*)d_in[2];
    const float* w3   = (const float*)d_in[3];
    const float* b3   = (const float*)d_in[4];
    const float* w2   = (const float*)d_in[5];
    const float* b2   = (const float*)d_in[6];
    float* out = (float*)d_out;
    char* ws = (char*)d_ws;
    bf16*    xbT    = (bf16*)(ws + OFF_XBT);
    bf16*    w3b    = (bf16*)(ws + OFF_W3B);
    bf16*    w2b    = (bf16*)(ws + OFF_W2B);
    float*   cvec   = (float*)(ws + OFF_CVEC);
    int*     pix2hw = (int*)(ws + OFF_PIX);
    float*   w1T    = (float*)(ws + OFF_W1T);
    float*   tabw   = (float*)(ws + OFF_TABW);
    uint8_t* tabt   = (uint8_t*)(ws + OFF_TABT);
    bf16*    x3     = (bf16*)(ws + OFF_X3);
    bf16*    bm     = (bf16*)(ws + OFF_BM);

    k_misc<<<dim3(813), dim3(256), 0, stream>>>(w1, w2, b2, b3, w3, w1T, w2b, w3b,
                                                cvec, pix2hw, tabw, tabt);
    k_conv<<<dim3(32, 8), dim3(256), 0, stream>>>(base, w1T, b1, xbT);
    k_bm<<<dim3(4160), dim3(256), 0, stream>>>(xbT, tabw, tabt, bm);
    k_gemm3f<<<dim3(520), dim3(256), 0, stream>>>(w3b, bm, b3, x3);
    k_gemm4<<<dim3(1284), dim3(256), 0, stream>>>(w2b, x3, b2, pix2hw, cvec, out);
}

// Round 10
// 379.064 us; speedup vs baseline: 1.2869x; 1.2869x over previous
//
#include <hip/hip_runtime.h>
#include <stdint.h>
#include <math.h>

typedef __bf16 bf16;
typedef __bf16 bf16x8 __attribute__((ext_vector_type(8)));
typedef float  f32x4  __attribute__((ext_vector_type(4)));

#define NVALID 2080            // D*(D+1)/2 valid (h<=w) pixels
#define NCOLS  16640           // B*NVALID  (bm rows, n-dim)
#define KDIM   4096            // NS*C2D    (bm cols, k = s*128+c)

// ws layout (bytes)
#define OFF_XBT   0u           // bf16 [8][256][128] = 512 KB
#define OFF_W3B   524288u      // bf16 [512][4096] (k=s*128+c) = 4 MB
#define OFF_W2B   4718592u     // bf16 [128][512]
#define OFF_CVEC  4849664u     // f32  [128]
#define OFF_PIX   4850176u     // int  [2080]
#define OFF_W1J   4859904u     // bf16 [128][768] = 196,608 (ends 5,056,512)
#define OFF_TABW  5253120u     // f32  [2080][32][8] = 2,129,920
#define OFF_TABT  7383040u     // u8   [2080][32][8] = 532,480 (ends 7,915,520)
#define OFF_X3    8388608u     // bf16 [16640][512] = 17,039,360 (ends 25,427,968)
#define OFF_BASET 25427968u    // bf16 [8][258][256] = 1,056,768 (ends 26,484,736)
#define OFF_BM    42991616u    // bf16 [16640][4096] = 136 MB (ends 179,306,496)

__device__ __forceinline__ void gload_lds16(const void* g, void* l) {
    __builtin_amdgcn_global_load_lds(
        (const __attribute__((address_space(1))) void*)g,
        (__attribute__((address_space(3))) void*)l, 16, 0, 0);
}

// Stage 16 rows x 32 k (bf16) into LDS with XOR swizzle.
__device__ __forceinline__ void stage16(const bf16* gbase, int stride, int rbase,
                                        int k0, bf16* ldsbase, int lane) {
    int row = rbase + (lane >> 2);
    int cg  = (lane & 3) ^ ((row >> 1) & 3);
    gload_lds16(gbase + (size_t)row * stride + k0 + cg * 8, ldsbase + rbase * 32);
}

__device__ __forceinline__ bf16x8 fragld(const bf16* lds, int row, int q) {
    int c = q ^ ((row >> 1) & 3);
    return *(const bf16x8*)(lds + row * 32 + c * 8);
}

// ---------------- misc mega-kernel ------------------------------------------
// grid 917: 0 = cvec+pix2hw; 1..16 = w2 cast; 17..528 = w3 transpose;
//           529..656 = w1 -> w1jb[co][j*256+ci]; 657..916 = sample table
__global__ __launch_bounds__(256) void k_misc(const float* __restrict__ w1,
                                              const float* __restrict__ w2,
                                              const float* __restrict__ b2,
                                              const float* __restrict__ b3,
                                              const float* __restrict__ w3,
                                              bf16* __restrict__ w1jb,
                                              bf16* __restrict__ w2b,
                                              bf16* __restrict__ w3b,
                                              float* __restrict__ cvec,
                                              int* __restrict__ pix2hw,
                                              float* __restrict__ tabw,
                                              uint8_t* __restrict__ tabt) {
    int tid = threadIdx.x, bx = blockIdx.x;
    if (bx == 0) {
        int wv = tid >> 6, ln = tid & 63;
        for (int c = wv; c < 128; c += 4) {
            const float* row = w2 + (size_t)c * 512 + ln * 8;
            float p = 0.f;
            #pragma unroll
            for (int k = 0; k < 8; k++) {
                float r = b3[ln * 8 + k]; r = r > 0.f ? r : 0.f;
                p += row[k] * r;
            }
            #pragma unroll
            for (int off = 32; off; off >>= 1) p += __shfl_down(p, off);
            if (ln == 0) {
                p += b2[c];
                cvec[c] = p > 0.f ? p : 0.f;
            }
        }
        for (int pix = tid; pix < NVALID; pix += 256) {
            int h = 0, base = 0;
            while (pix >= base + (64 - h)) { base += 64 - h; h++; }
            int w = h + (pix - base);
            pix2hw[pix] = h * 64 + w;
        }
    } else if (bx <= 16) {
        int i = ((bx - 1) * 256 + tid) * 16;
        #pragma unroll
        for (int j = 0; j < 16; j++) w2b[i + j] = (bf16)w2[i + j];
    } else if (bx <= 528) {
        // transpose one o row: w3[o][c][s] -> w3b[o][s*128+c]
        __shared__ float l[128 * 33];
        int o = bx - 17;
        const float* src = w3 + (size_t)o * 4096;
        #pragma unroll
        for (int m = 0; m < 16; m++) {
            int i = m * 256 + tid;
            int c = i >> 5, s = i & 31;
            l[c * 33 + s] = src[i];
        }
        __syncthreads();
        bf16* d = w3b + (size_t)o * 4096;
        #pragma unroll
        for (int m = 0; m < 16; m++) {
            int k = m * 256 + tid;
            int s = k >> 7, c = k & 127;
            d[k] = (bf16)l[c * 33 + s];
        }
    } else if (bx <= 656) {
        // one co per block: w1[co][ci][j] -> w1jb[co][j*256+ci]
        __shared__ float l[768];
        int co = bx - 529;
        const float* src = w1 + (size_t)co * 768;
        l[tid] = src[tid]; l[tid + 256] = src[tid + 256]; l[tid + 512] = src[tid + 512];
        __syncthreads();
        bf16* d = w1jb + (size_t)co * 768;
        #pragma unroll
        for (int m = 0; m < 3; m++) {
            int k = m * 256 + tid;               // k = j*256+ci
            d[k] = (bf16)l[(k & 255) * 3 + (k >> 8)];
        }
    } else {
        // sample table: per (pix,s) 6 (t, weight) pairs, double-exact
        int idx = (bx - 657) * 256 + tid;   // p*32+s
        if (idx >= NVALID * 32) return;
        int p = idx >> 5, s = idx & 31;
        int h = 0, base = 0;
        while (p >= base + (64 - h)) { base += 64 - h; h++; }
        int w = h + (p - base);
        double sp = 4.0 * h, ep = 4.0 * (w + 1);
        double L = ep - sp + 1.0;
        double start_p = sp - L * 0.5;
        double end_p   = ep + L * 0.5;
        double step = (end_p - start_p) / 95.0;
        float*   wd = tabw + (size_t)idx * 8;
        uint8_t* td = tabt + (size_t)idx * 8;
        #pragma unroll
        for (int i = 0; i < 3; i++) {
            double pos = start_p + step * (3 * s + i);
            double tr = trunc(pos);
            double fr = pos - tr;
            int it = (int)tr;
            bool ok = (it >= 0 && it < 255);
            wd[i*2+0] = ok ? (float)((1.0 - fr) / 3.0) : 0.f;
            td[i*2+0] = (uint8_t)(ok ? it : 0);
            wd[i*2+1] = ok ? (float)(fr / 3.0) : 0.f;
            td[i*2+1] = (uint8_t)(ok ? it + 1 : 0);
        }
        wd[6] = 0.f; wd[7] = 0.f; td[6] = 0; td[7] = 0;
    }
}

// ---------------- transpose+cast: base[b][ci][t] -> baseT[b][1+t][ci] bf16 ---
// grid 129: blocks 0..127 do 64x64 tiles; block 128 zeroes pad rows 0 & 257.
__global__ __launch_bounds__(256) void k_tr(const float* __restrict__ base,
                                            bf16* __restrict__ baseT) {
    int tid = threadIdx.x;
    if (blockIdx.x == 128) {
        for (int k = tid; k < 8 * 2 * 256; k += 256) {
            int b = k >> 9, rr = (k >> 8) & 1, ci = k & 255;
            baseT[((size_t)b * 258 + rr * 257) * 256 + ci] = (bf16)0.f;
        }
        return;
    }
    __shared__ float l[64][65];
    int id = blockIdx.x;
    int b = id >> 4, ci0 = ((id >> 2) & 3) * 64, t0 = (id & 3) * 64;
    #pragma unroll
    for (int m = 0; m < 16; m++) {
        int idx = m * 256 + tid;
        int ci_l = idx >> 6, t_l = idx & 63;
        l[ci_l][t_l] = base[((size_t)b * 256 + ci0 + ci_l) * 256 + t0 + t_l];
    }
    __syncthreads();
    #pragma unroll
    for (int m = 0; m < 16; m++) {
        int idx = m * 256 + tid;
        int t_l = idx >> 6, ci_l = idx & 63;
        baseT[((size_t)b * 258 + 1 + t0 + t_l) * 256 + ci0 + ci_l] = (bf16)l[ci_l][t_l];
    }
}

// ---------------- conv as GEMM: xbT[b][t][co] = relu(A @ w1jb^T + b1) --------
// A row (b,t) = baseT[b*258+t .. +2][:] = 768 contiguous bf16 (t-1..t+1 halo).
// Tile 128t x 128co, K=768 (24 iters), grid 16 (b, thalf).
__global__ __launch_bounds__(256, 2) void k_cgemm(const bf16* __restrict__ baseT,
                                                  const bf16* __restrict__ w1jb,
                                                  const float* __restrict__ b1,
                                                  bf16* __restrict__ xbT) {
    __shared__ __align__(16) char lds[34816];
    bf16* As0 = (bf16*)lds;              // [2][128][32]
    bf16* Bs0 = (bf16*)(lds + 16384);    // [2][128][32]
    bf16* T2  = (bf16*)lds;              // [128][136] epilogue

    int tid = threadIdx.x, lane = tid & 63, wave = tid >> 6;
    int m16 = lane & 15, q = lane >> 4;
    int wm = wave >> 1, wn = wave & 1;
    int id = blockIdx.x;
    int b = id >> 1, t_base = (id & 1) * 128;
    const bf16* Ag = baseT + ((size_t)b * 258 + t_base) * 256;
    const bf16* Bg = w1jb;

    f32x4 acc[4][4];
    #pragma unroll
    for (int i = 0; i < 4; i++)
        #pragma unroll
        for (int j = 0; j < 4; j++) acc[i][j] = (f32x4){0.f, 0.f, 0.f, 0.f};

    stage16(Ag, 256, wave * 32,      0, As0, lane);
    stage16(Ag, 256, wave * 32 + 16, 0, As0, lane);
    stage16(Bg, 768, wave * 32,      0, Bs0, lane);
    stage16(Bg, 768, wave * 32 + 16, 0, Bs0, lane);

    for (int ks = 0; ks < 24; ks++) {
        __syncthreads();
        if (ks < 23) {
            int k0 = (ks + 1) * 32, o = ((ks + 1) & 1) * 4096;
            stage16(Ag, 256, wave * 32,      k0, As0 + o, lane);
            stage16(Ag, 256, wave * 32 + 16, k0, As0 + o, lane);
            stage16(Bg, 768, wave * 32,      k0, Bs0 + o, lane);
            stage16(Bg, 768, wave * 32 + 16, k0, Bs0 + o, lane);
        }
        const bf16* Ac = As0 + (ks & 1) * 4096;
        const bf16* Bc = Bs0 + (ks & 1) * 4096;
        bf16x8 af[4], bfv[4];
        #pragma unroll
        for (int i = 0; i < 4; i++) af[i]  = fragld(Ac, wm * 64 + i * 16 + m16, q);
        #pragma unroll
        for (int j = 0; j < 4; j++) bfv[j] = fragld(Bc, wn * 64 + j * 16 + m16, q);
        #pragma unroll
        for (int i = 0; i < 4; i++)
            #pragma unroll
            for (int j = 0; j < 4; j++)
                acc[i][j] = __builtin_amdgcn_mfma_f32_16x16x32_bf16(af[i], bfv[j], acc[i][j], 0, 0, 0);
    }
    __syncthreads();
    float biasj[4];
    #pragma unroll
    for (int j = 0; j < 4; j++) biasj[j] = b1[wn * 64 + j * 16 + m16];
    #pragma unroll
    for (int i = 0; i < 4; i++)
        #pragma unroll
        for (int r = 0; r < 4; r++) {
            int m_l = wm * 64 + i * 16 + q * 4 + r;
            #pragma unroll
            for (int j = 0; j < 4; j++) {
                int co_l = wn * 64 + j * 16 + m16;
                float v = acc[i][j][r] + biasj[j]; v = v > 0.f ? v : 0.f;
                T2[m_l * 136 + co_l] = (bf16)v;
            }
        }
    __syncthreads();
    {
        int m_l = tid >> 1, half = (tid & 1) * 64;
        bf16* dst = xbT + (size_t)(b * 256 + t_base + m_l) * 128 + half;
        const bf16* src = T2 + m_l * 136 + half;
        #pragma unroll
        for (int m = 0; m < 8; m++)
            *(bf16x8*)(dst + m * 8) = *(const bf16x8*)(src + m * 8);
    }
}

// ---------------- bm sparse (R8-proven): one wave per bm row -----------------
__global__ __launch_bounds__(256) void k_bm(const bf16* __restrict__ xbT,
                                            const float* __restrict__ tabw,
                                            const uint8_t* __restrict__ tabt,
                                            bf16* __restrict__ bm) {
    int lane = threadIdx.x & 63;
    int n = __builtin_amdgcn_readfirstlane(blockIdx.x * 4 + (threadIdx.x >> 6));
    int b = n / NVALID, p = n - b * NVALID;
    const bf16* xs = xbT + (size_t)b * 32768;
    bf16* dst = bm + (size_t)n * (size_t)KDIM;
    for (int s = 0; s < 32; s++) {
        const float*   wv = tabw + (size_t)(p * 32 + s) * 8;
        const uint8_t* tv = tabt + (size_t)(p * 32 + s) * 8;
        float a0 = 0.f, a1 = 0.f;
        #pragma unroll
        for (int j = 0; j < 6; j++) {
            float w = wv[j];
            int   t = tv[j];
            uint32_t x = *(const uint32_t*)(xs + t * 128 + lane * 2);
            union { uint32_t u; float f; } lo, hi;
            lo.u = x << 16;
            hi.u = x & 0xffff0000u;
            a0 += w * lo.f;
            a1 += w * hi.f;
        }
        union { uint32_t u; bf16 h[2]; } o;
        o.h[0] = (bf16)a0; o.h[1] = (bf16)a1;
        *(uint32_t*)(dst + s * 128 + lane * 2) = o.u;
    }
}

// ---------------- GEMM3 (proven): x3[n][o] = relu(w3b @ bm^T + b3) -----------
__global__ __launch_bounds__(256, 2) void k_gemm3f(const bf16* __restrict__ w3b,
                                                   const bf16* __restrict__ bm,
                                                   const float* __restrict__ b3,
                                                   bf16* __restrict__ x3) {
    __shared__ __align__(16) char lds[34816];
    bf16* As0 = (bf16*)lds;
    bf16* Bs0 = (bf16*)(lds + 16384);
    bf16* T2  = (bf16*)lds;

    int tid = threadIdx.x, lane = tid & 63, wave = tid >> 6;
    int m16 = lane & 15, q = lane >> 4;
    int wm = wave >> 1, wn = wave & 1;
    int id = blockIdx.x, nt, ot;
    if (id >= 512) { int r = id - 512; nt = 128 + (r & 1); ot = r >> 1; }
    else           { nt = (id >> 5) * 8 + (id & 7); ot = (id >> 3) & 3; }
    int n0 = nt * 128, o0 = ot * 128;
    const bf16* Ag = w3b + (size_t)o0 * KDIM;
    const bf16* Bg = bm + (size_t)n0 * KDIM;

    f32x4 acc[4][4];
    #pragma unroll
    for (int i = 0; i < 4; i++)
        #pragma unroll
        for (int j = 0; j < 4; j++) acc[i][j] = (f32x4){0.f, 0.f, 0.f, 0.f};

    stage16(Ag, KDIM, wave * 32,      0, As0, lane);
    stage16(Ag, KDIM, wave * 32 + 16, 0, As0, lane);
    stage16(Bg, KDIM, wave * 32,      0, Bs0, lane);
    stage16(Bg, KDIM, wave * 32 + 16, 0, Bs0, lane);

    for (int ks = 0; ks < 128; ks++) {
        __syncthreads();
        if (ks < 127) {
            int k0 = (ks + 1) * 32, o = ((ks + 1) & 1) * 4096;
            stage16(Ag, KDIM, wave * 32,      k0, As0 + o, lane);
            stage16(Ag, KDIM, wave * 32 + 16, k0, As0 + o, lane);
            stage16(Bg, KDIM, wave * 32,      k0, Bs0 + o, lane);
            stage16(Bg, KDIM, wave * 32 + 16, k0, Bs0 + o, lane);
        }
        const bf16* Ac = As0 + (ks & 1) * 4096;
        const bf16* Bc = Bs0 + (ks & 1) * 4096;
        bf16x8 af[4], bfv[4];
        #pragma unroll
        for (int i = 0; i < 4; i++) af[i]  = fragld(Ac, wm * 64 + i * 16 + m16, q);
        #pragma unroll
        for (int j = 0; j < 4; j++) bfv[j] = fragld(Bc, wn * 64 + j * 16 + m16, q);
        #pragma unroll
        for (int i = 0; i < 4; i++)
            #pragma unroll
            for (int j = 0; j < 4; j++)
                acc[i][j] = __builtin_amdgcn_mfma_f32_16x16x32_bf16(af[i], bfv[j], acc[i][j], 0, 0, 0);
    }
    __syncthreads();
    #pragma unroll
    for (int i = 0; i < 4; i++)
        #pragma unroll
        for (int r = 0; r < 4; r++) {
            int o_l = wm * 64 + i * 16 + q * 4 + r;
            float bias = b3[o0 + o_l];
            #pragma unroll
            for (int j = 0; j < 4; j++) {
                int n_l = wn * 64 + j * 16 + m16;
                float v = acc[i][j][r] + bias; v = v > 0.f ? v : 0.f;
                T2[n_l * 136 + o_l] = (bf16)v;
            }
        }
    __syncthreads();
    {
        int n_l = tid >> 1, half = (tid & 1) * 64;
        bf16* dst = x3 + (size_t)(n0 + n_l) * 512 + o0 + half;
        const bf16* src = T2 + n_l * 136 + half;
        #pragma unroll
        for (int m = 0; m < 8; m++)
            *(bf16x8*)(dst + m * 8) = *(const bf16x8*)(src + m * 8);
    }
}

// ---------------- GEMM4 + fill: blocks [0,260) gemm, [260,1284) fill ---------
__global__ __launch_bounds__(256, 2) void k_gemm4(const bf16* __restrict__ w2b,
                                                  const bf16* __restrict__ x3,
                                                  const float* __restrict__ b2,
                                                  const int* __restrict__ pix2hw,
                                                  const float* __restrict__ cvec,
                                                  float* __restrict__ out) {
    __shared__ __align__(16) char lds[24576];
    if (blockIdx.x >= 260) {
        int bo = blockIdx.x - 260;           // b*128 + o2
        float v = cvec[bo & 127];
        float* dst = out + (size_t)bo * 4096;
        for (int hw = threadIdx.x; hw < 4096; hw += 256) {
            int h = hw >> 6, w = hw & 63;
            if (w < h) dst[hw] = v;
        }
        return;
    }
    bf16* As0 = (bf16*)lds;
    bf16* Bs0 = (bf16*)(lds + 16384);

    int tid = threadIdx.x, lane = tid & 63, wave = tid >> 6;
    int m16 = lane & 15, q = lane >> 4;
    int n0 = blockIdx.x * 64;
    const bf16* Ag = w2b;
    const bf16* Bg = x3 + (size_t)n0 * 512;

    f32x4 acc[2][4];
    #pragma unroll
    for (int i = 0; i < 2; i++)
        #pragma unroll
        for (int j = 0; j < 4; j++) acc[i][j] = (f32x4){0.f, 0.f, 0.f, 0.f};

    stage16(Ag, 512, wave * 32,      0, As0, lane);
    stage16(Ag, 512, wave * 32 + 16, 0, As0, lane);
    stage16(Bg, 512, wave * 16,      0, Bs0, lane);

    for (int ks = 0; ks < 16; ks++) {
        __syncthreads();
        if (ks < 15) {
            int k0 = (ks + 1) * 32, oA = ((ks + 1) & 1) * 4096, oB = ((ks + 1) & 1) * 2048;
            stage16(Ag, 512, wave * 32,      k0, As0 + oA, lane);
            stage16(Ag, 512, wave * 32 + 16, k0, As0 + oA, lane);
            stage16(Bg, 512, wave * 16,      k0, Bs0 + oB, lane);
        }
        const bf16* Ac = As0 + (ks & 1) * 4096;
        const bf16* Bc = Bs0 + (ks & 1) * 2048;
        bf16x8 af[2], bfv[4];
        #pragma unroll
        for (int i = 0; i < 2; i++) af[i]  = fragld(Ac, wave * 32 + i * 16 + m16, q);
        #pragma unroll
        for (int j = 0; j < 4; j++) bfv[j] = fragld(Bc, j * 16 + m16, q);
        #pragma unroll
        for (int i = 0; i < 2; i++)
            #pragma unroll
            for (int j = 0; j < 4; j++)
                acc[i][j] = __builtin_amdgcn_mfma_f32_16x16x32_bf16(af[i], bfv[j], acc[i][j], 0, 0, 0);
    }
    int barr[4], hwarr[4];
    #pragma unroll
    for (int j = 0; j < 4; j++) {
        int n = n0 + j * 16 + m16;
        int bb = n / NVALID;
        barr[j] = bb; hwarr[j] = pix2hw[n - bb * NVALID];
    }
    #pragma unroll
    for (int i = 0; i < 2; i++)
        #pragma unroll
        for (int r = 0; r < 4; r++) {
            int o2 = wave * 32 + i * 16 + q * 4 + r;
            float bias = b2[o2];
            #pragma unroll
            for (int j = 0; j < 4; j++) {
                float v = acc[i][j][r] + bias; v = v > 0.f ? v : 0.f;
                out[(size_t)barr[j] * 524288 + o2 * 4096 + hwarr[j]] = v;
            }
        }
}

extern "C" void kernel_launch(void* const* d_in, const int* in_sizes, int n_in,
                              void* d_out, int out_size, void* d_ws, size_t ws_size,
                              hipStream_t stream) {
    const float* base = (const float*)d_in[0];
    const float* w1   = (const float*)d_in[1];
    const float* b1   = (const float*)d_in[2];
    const float* w3   = (const float*)d_in[3];
    const float* b3   = (const float*)d_in[4];
    const float* w2   = (const float*)d_in[5];
    const float* b2   = (const float*)d_in[6];
    float* out = (float*)d_out;
    char* ws = (char*)d_ws;
    bf16*    xbT    = (bf16*)(ws + OFF_XBT);
    bf16*    w3b    = (bf16*)(ws + OFF_W3B);
    bf16*    w2b    = (bf16*)(ws + OFF_W2B);
    float*   cvec   = (float*)(ws + OFF_CVEC);
    int*     pix2hw = (int*)(ws + OFF_PIX);
    bf16*    w1jb   = (bf16*)(ws + OFF_W1J);
    float*   tabw   = (float*)(ws + OFF_TABW);
    uint8_t* tabt   = (uint8_t*)(ws + OFF_TABT);
    bf16*    x3     = (bf16*)(ws + OFF_X3);
    bf16*    baseT  = (bf16*)(ws + OFF_BASET);
    bf16*    bm     = (bf16*)(ws + OFF_BM);

    k_misc<<<dim3(917), dim3(256), 0, stream>>>(w1, w2, b2, b3, w3, w1jb, w2b, w3b,
                                                cvec, pix2hw, tabw, tabt);
    k_tr<<<dim3(129), dim3(256), 0, stream>>>(base, baseT);
    k_cgemm<<<dim3(16), dim3(256), 0, stream>>>(baseT, w1jb, b1, xbT);
    k_bm<<<dim3(4160), dim3(256), 0, stream>>>(xbT, tabw, tabt, bm);
    k_gemm3f<<<dim3(520), dim3(256), 0, stream>>>(w3b, bm, b3, x3);
    k_gemm4<<<dim3(1284), dim3(256), 0, stream>>>(w2b, x3, b2, pix2hw, cvec, out);
}